// Round 1
// baseline (181.936 us; speedup 1.0000x reference)
//
#include <hip/hip_runtime.h>
#include <stdint.h>

typedef unsigned long long u64;

#define NUM_TRAIN   50000
#define NUM_TEST    4096
#define CLASS_SIZE  5000
#define TT          8      // test samples per block in knn kernel

// ---------------------------------------------------------------------------
// Pack kernel: one wave (64 lanes) per 256-int row. Each lane loads int4
// (contiguous 1024B per wave). 4x __ballot produces 4 u64 words. The bit
// order is a fixed permutation of the row — consistent across train/test, and
// XOR+popcount is permutation-invariant, so Hamming distances are unchanged.
// ---------------------------------------------------------------------------
__global__ void pack_kernel(const int* __restrict__ train,
                            const int* __restrict__ test,
                            u64* __restrict__ packed) {
    int wave = (blockIdx.x * blockDim.x + threadIdx.x) >> 6;
    int lane = threadIdx.x & 63;
    const int* src = (wave < NUM_TRAIN)
                       ? (train + (size_t)wave * 256)
                       : (test + (size_t)(wave - NUM_TRAIN) * 256);
    int4 v = *reinterpret_cast<const int4*>(src + lane * 4);
    u64 b0 = __ballot(v.x & 1);
    u64 b1 = __ballot(v.y & 1);
    u64 b2 = __ballot(v.z & 1);
    u64 b3 = __ballot(v.w & 1);
    if (lane == 0) {
        u64* dst = packed + (size_t)wave * 4;
        dst[0] = b0; dst[1] = b1; dst[2] = b2; dst[3] = b3;
    }
}

// Sorted-insert key into (k0<=k1<=k2), keeping the 3 smallest.
__device__ __forceinline__ void insert3(unsigned& k0, unsigned& k1,
                                        unsigned& k2, unsigned key) {
    unsigned m0 = min(k0, key);
    unsigned m1 = min(k1, max(k0, key));
    unsigned m2 = min(k2, max(k1, key));
    k0 = m0; k1 = m1; k2 = m2;
}

// ---------------------------------------------------------------------------
// KNN kernel: block = 256 threads handles TT=8 test samples (rows held in
// registers). Threads stride over the 50000 training rows; per pair:
// dist = sum popcll(xor) over 4 u64; key = (dist<<16)|train_idx so min-key
// order == (dist, then smaller index) — exactly the reference tie-break.
// ---------------------------------------------------------------------------
__global__ __launch_bounds__(256) void knn_kernel(const u64* __restrict__ packed,
                                                  int* __restrict__ out) {
    const u64* trainp = packed;
    const u64* testp  = packed + (size_t)NUM_TRAIN * 4;
    const int  base   = blockIdx.x * TT;
    const int  tid    = threadIdx.x;

    u64 te[TT][4];
    #pragma unroll
    for (int s = 0; s < TT; ++s) {
        const u64* p = testp + (size_t)(base + s) * 4;
        te[s][0] = p[0]; te[s][1] = p[1]; te[s][2] = p[2]; te[s][3] = p[3];
    }

    unsigned k0[TT], k1[TT], k2[TT];
    #pragma unroll
    for (int s = 0; s < TT; ++s) { k0[s] = k1[s] = k2[s] = 0x7FFFFFFFu; }

    for (int r = tid; r < NUM_TRAIN; r += 256) {
        const u64* p = trainp + (size_t)r * 4;
        u64 t0 = p[0], t1 = p[1], t2 = p[2], t3 = p[3];
        #pragma unroll
        for (int s = 0; s < TT; ++s) {
            int d = __popcll(t0 ^ te[s][0]) + __popcll(t1 ^ te[s][1])
                  + __popcll(t2 ^ te[s][2]) + __popcll(t3 ^ te[s][3]);
            unsigned key = ((unsigned)d << 16) | (unsigned)r;
            insert3(k0[s], k1[s], k2[s], key);
        }
    }

    // Wave-level butterfly merge of sorted triples (3-smallest is
    // associative/commutative/idempotent, so butterfly converges all lanes).
    #pragma unroll
    for (int s = 0; s < TT; ++s) {
        for (int off = 1; off < 64; off <<= 1) {
            unsigned o0 = __shfl_xor(k0[s], off);
            unsigned o1 = __shfl_xor(k1[s], off);
            unsigned o2 = __shfl_xor(k2[s], off);
            insert3(k0[s], k1[s], k2[s], o0);
            insert3(k0[s], k1[s], k2[s], o1);
            insert3(k0[s], k1[s], k2[s], o2);
        }
    }

    __shared__ unsigned red[4][TT][3];
    const int wave = tid >> 6, lane = tid & 63;
    if (lane == 0) {
        #pragma unroll
        for (int s = 0; s < TT; ++s) {
            red[wave][s][0] = k0[s];
            red[wave][s][1] = k1[s];
            red[wave][s][2] = k2[s];
        }
    }
    __syncthreads();

    if (tid < TT) {
        const int s = tid;
        unsigned a0 = red[0][s][0], a1 = red[0][s][1], a2 = red[0][s][2];
        #pragma unroll
        for (int w = 1; w < 4; ++w) {
            insert3(a0, a1, a2, red[w][s][0]);
            insert3(a0, a1, a2, red[w][s][1]);
            insert3(a0, a1, a2, red[w][s][2]);
        }
        const int l0 = (int)(a0 & 0xFFFFu) / CLASS_SIZE;
        const int l1 = (int)(a1 & 0xFFFFu) / CLASS_SIZE;
        const int l2 = (int)(a2 & 0xFFFFu) / CLASS_SIZE;
        int winner;
        if (l0 == l1 || l0 == l2)      winner = l0;    // count(l0) >= 2
        else if (l1 == l2)             winner = l1;    // count(l1) == 2
        else winner = min(l0, min(l1, l2));            // 1-1-1 tie: argmax picks first
        out[base + s] = winner;
    }
}

extern "C" void kernel_launch(void* const* d_in, const int* in_sizes, int n_in,
                              void* d_out, int out_size, void* d_ws, size_t ws_size,
                              hipStream_t stream) {
    const int* train = (const int*)d_in[0];
    const int* test  = (const int*)d_in[1];
    int* out = (int*)d_out;
    u64* packed = (u64*)d_ws;   // (50000+4096) rows * 4 u64 = 1.73 MB

    const int total_rows = NUM_TRAIN + NUM_TEST;      // 54096, divisible by 4
    pack_kernel<<<total_rows / 4, 256, 0, stream>>>(train, test, packed);
    knn_kernel<<<NUM_TEST / TT, 256, 0, stream>>>(packed, out);
}

// Round 2
// 149.583 us; speedup vs baseline: 1.2163x; 1.2163x over previous
//
#include <hip/hip_runtime.h>
#include <stdint.h>

typedef unsigned long long u64;

#define NUM_TRAIN   50000
#define NUM_TEST    4096
#define CLASS_SIZE  5000
#define TT          8      // test samples per block in knn kernel
#define NCHUNK      4      // training-set chunks (occupancy: 2048 blocks)
#define CHUNK_ROWS  (NUM_TRAIN / NCHUNK)   // 12500

// ---------------------------------------------------------------------------
// Pack kernel: one wave per 256-int row; 4x __ballot -> 4 u64. Bit order is a
// fixed permutation (consistent train/test), XOR+popcount is invariant to it.
// ---------------------------------------------------------------------------
__global__ void pack_kernel(const int* __restrict__ train,
                            const int* __restrict__ test,
                            u64* __restrict__ packed) {
    int wave = (blockIdx.x * blockDim.x + threadIdx.x) >> 6;
    int lane = threadIdx.x & 63;
    const int* src = (wave < NUM_TRAIN)
                       ? (train + (size_t)wave * 256)
                       : (test + (size_t)(wave - NUM_TRAIN) * 256);
    int4 v = *reinterpret_cast<const int4*>(src + lane * 4);
    u64 b0 = __ballot(v.x & 1);
    u64 b1 = __ballot(v.y & 1);
    u64 b2 = __ballot(v.z & 1);
    u64 b3 = __ballot(v.w & 1);
    if (lane == 0) {
        u64* dst = packed + (size_t)wave * 4;
        dst[0] = b0; dst[1] = b1; dst[2] = b2; dst[3] = b3;
    }
}

__device__ __forceinline__ unsigned umin_(unsigned a, unsigned b) { return a < b ? a : b; }
__device__ __forceinline__ unsigned umax_(unsigned a, unsigned b) { return a > b ? a : b; }

// Sorted-insert key into (k0<=k1<=k2), keeping the 3 smallest. 5 VALU.
__device__ __forceinline__ void insert3(unsigned& k0, unsigned& k1,
                                        unsigned& k2, unsigned key) {
    unsigned m0 = umin_(k0, key);
    unsigned m1 = umin_(k1, umax_(k0, key));
    unsigned m2 = umin_(k2, umax_(k1, key));
    k0 = m0; k1 = m1; k2 = m2;
}

// Merge two sorted triples -> sorted top-3 of the union. 7 VALU.
__device__ __forceinline__ void merge3(unsigned& a0, unsigned& a1, unsigned& a2,
                                       unsigned b0, unsigned b1, unsigned b2) {
    unsigned hi0 = umax_(a0, b0);          // 2nd-smallest candidate
    unsigned lo1 = umin_(a1, b1);
    unsigned c0  = umin_(a0, b0);
    unsigned c1  = umin_(hi0, lo1);
    unsigned c2  = umin_(umax_(lo1, hi0), umin_(a2, b2));
    a0 = c0; a1 = c1; a2 = c2;
}

// ---------------------------------------------------------------------------
// KNN kernel: block (g,c) = sample-group g (TT=8 rows, in SGPRs via uniform
// s_load) x training chunk c (12500 rows). Threads stride the chunk; key =
// (dist<<16)|train_idx encodes the reference (dist, smaller-index) tie-break.
// Partial top-3 per (sample, chunk) -> ws; merged by merge_kernel.
// ---------------------------------------------------------------------------
__global__ __launch_bounds__(256) void knn_kernel(const u64* __restrict__ packed,
                                                  unsigned* __restrict__ partial) {
    const int g   = blockIdx.x >> 2;       // sample group (0..511)
    const int c   = blockIdx.x & 3;        // chunk (0..3)
    const int tid = threadIdx.x;
    const int base = g * TT;
    const u64* trainp = packed;
    const u64* testp  = packed + (size_t)NUM_TRAIN * 4;

    u64 te[TT][4];   // block-uniform addresses -> compiler keeps these in SGPRs
    #pragma unroll
    for (int s = 0; s < TT; ++s) {
        const u64* p = testp + (size_t)(base + s) * 4;
        te[s][0] = p[0]; te[s][1] = p[1]; te[s][2] = p[2]; te[s][3] = p[3];
    }

    unsigned k0[TT], k1[TT], k2[TT];
    #pragma unroll
    for (int s = 0; s < TT; ++s) { k0[s] = k1[s] = k2[s] = 0x7FFFFFFFu; }

    const int start = c * CHUNK_ROWS;
    const int end   = start + CHUNK_ROWS;
    for (int r = start + tid; r < end; r += 256) {
        const u64* p = trainp + (size_t)r * 4;
        u64 t0 = p[0], t1 = p[1], t2 = p[2], t3 = p[3];
        #pragma unroll
        for (int s = 0; s < TT; ++s) {
            int d = __popcll(t0 ^ te[s][0]) + __popcll(t1 ^ te[s][1])
                  + __popcll(t2 ^ te[s][2]) + __popcll(t3 ^ te[s][3]);
            unsigned key = ((unsigned)d << 16) | (unsigned)r;
            insert3(k0[s], k1[s], k2[s], key);
        }
    }

    // Wave butterfly: top-3 merge is idempotent/commutative/associative,
    // so xor-butterfly converges all 64 lanes to the wave-wide top-3.
    #pragma unroll
    for (int s = 0; s < TT; ++s) {
        for (int off = 1; off < 64; off <<= 1) {
            unsigned o0 = __shfl_xor(k0[s], off);
            unsigned o1 = __shfl_xor(k1[s], off);
            unsigned o2 = __shfl_xor(k2[s], off);
            merge3(k0[s], k1[s], k2[s], o0, o1, o2);
        }
    }

    __shared__ unsigned red[4][TT][3];
    const int wave = tid >> 6, lane = tid & 63;
    if (lane == 0) {
        #pragma unroll
        for (int s = 0; s < TT; ++s) {
            red[wave][s][0] = k0[s];
            red[wave][s][1] = k1[s];
            red[wave][s][2] = k2[s];
        }
    }
    __syncthreads();

    if (tid < TT) {
        const int s = tid;
        unsigned a0 = red[0][s][0], a1 = red[0][s][1], a2 = red[0][s][2];
        #pragma unroll
        for (int w = 1; w < 4; ++w)
            merge3(a0, a1, a2, red[w][s][0], red[w][s][1], red[w][s][2]);
        unsigned* dst = partial + ((size_t)(base + s) * NCHUNK + c) * 3;
        dst[0] = a0; dst[1] = a1; dst[2] = a2;
    }
}

// ---------------------------------------------------------------------------
// Merge kernel: one thread per test sample; merge NCHUNK partial triples,
// derive labels, majority vote with argmax-first-max tie semantics.
// ---------------------------------------------------------------------------
__global__ __launch_bounds__(256) void merge_kernel(const unsigned* __restrict__ partial,
                                                    int* __restrict__ out) {
    int t = blockIdx.x * blockDim.x + threadIdx.x;
    if (t >= NUM_TEST) return;
    const unsigned* p = partial + (size_t)t * NCHUNK * 3;
    unsigned a0 = p[0], a1 = p[1], a2 = p[2];
    #pragma unroll
    for (int c = 1; c < NCHUNK; ++c)
        merge3(a0, a1, a2, p[c * 3 + 0], p[c * 3 + 1], p[c * 3 + 2]);
    const int l0 = (int)(a0 & 0xFFFFu) / CLASS_SIZE;
    const int l1 = (int)(a1 & 0xFFFFu) / CLASS_SIZE;
    const int l2 = (int)(a2 & 0xFFFFu) / CLASS_SIZE;
    int winner;
    if (l0 == l1 || l0 == l2)      winner = l0;    // count(l0) >= 2
    else if (l1 == l2)             winner = l1;    // count(l1) == 2
    else winner = min(l0, min(l1, l2));            // 1-1-1: argmax picks first max
    out[t] = winner;
}

extern "C" void kernel_launch(void* const* d_in, const int* in_sizes, int n_in,
                              void* d_out, int out_size, void* d_ws, size_t ws_size,
                              hipStream_t stream) {
    const int* train = (const int*)d_in[0];
    const int* test  = (const int*)d_in[1];
    int* out = (int*)d_out;

    u64* packed = (u64*)d_ws;   // (50000+4096) rows * 32 B = 1.73 MB
    unsigned* partial = (unsigned*)((char*)d_ws + (size_t)(NUM_TRAIN + NUM_TEST) * 4 * sizeof(u64));
    // partial: 4096 * 4 * 3 * 4 B = 192 KB  (total ws use ~1.93 MB)

    const int total_rows = NUM_TRAIN + NUM_TEST;      // 54096, divisible by 4
    pack_kernel<<<total_rows / 4, 256, 0, stream>>>(train, test, packed);
    knn_kernel<<<(NUM_TEST / TT) * NCHUNK, 256, 0, stream>>>(packed, partial);
    merge_kernel<<<(NUM_TEST + 255) / 256, 256, 0, stream>>>(partial, out);
}